// Round 13
// baseline (766.480 us; speedup 1.0000x reference)
//
#include <hip/hip_runtime.h>
#include <hip/hip_bf16.h>
#include <math.h>

typedef __attribute__((ext_vector_type(8))) short short8;
typedef __attribute__((ext_vector_type(4))) short short4v;
typedef __attribute__((ext_vector_type(4))) float f32x4;
typedef __attribute__((ext_vector_type(2))) float f32x2;

__device__ __forceinline__ float bs2f(short s){
    union { unsigned u; float f; } x; x.u = ((unsigned)(unsigned short)s) << 16; return x.f;
}
__device__ __forceinline__ short f2bs(float f){
    union { float f; unsigned u; } x; x.f = f;
    unsigned r = x.u + 0x7fff + ((x.u >> 16) & 1);   // round-nearest-even
    return (short)(r >> 16);
}
__device__ __forceinline__ f32x2 up2(unsigned u){   // unpack 2 bf16 -> float2
    union { unsigned u; float f; } lo, hi;
    lo.u = u << 16; hi.u = u & 0xffff0000u;
    f32x2 r; r.x = lo.f; r.y = hi.f; return r;
}
__device__ __forceinline__ unsigned pk2rn(float lo, float hi){  // RNE pack
    __hip_bfloat162 h = __float22bfloat162_rn(make_float2(lo, hi));
    union { __hip_bfloat162 h; unsigned u; } cv; cv.h = h; return cv.u;
}
__device__ __forceinline__ void gl2lds16(const void* g, void* l){
    __builtin_amdgcn_global_load_lds(
        (const __attribute__((address_space(1))) void*)g,
        (__attribute__((address_space(3))) void*)l, 16, 0, 0);
}
__device__ __forceinline__ void hard_barrier(){
    __builtin_amdgcn_sched_barrier(0);
    __builtin_amdgcn_s_barrier();
    __builtin_amdgcn_sched_barrier(0);
}
// barrier that drains ONLY LDS ops (keeps global register-loads in flight)
__device__ __forceinline__ void lds_barrier(){
    __builtin_amdgcn_sched_barrier(0);
    asm volatile("s_waitcnt lgkmcnt(0)" ::: "memory");
    __builtin_amdgcn_s_barrier();
    __builtin_amdgcn_sched_barrier(0);
}

// Xpad[b][y][x][c]: y,x in [0,66), c in [0,512). Interior (y=h+1,x=w+1).
// c<256: flipped feature (= feature[b][c][h][63-w]); c>=256: proj.
#define XPB ((size_t)66*66*512)

// LDS k-quad XOR swizzle (B tiles): LDS quad p of row r holds global quad
// p^((r>>1)&3); fragment read for (row ln, quad q) uses LDS quad q^((ln>>1)&3).

// ---------------- prep: BN folding + weight transposes + Xpad halo zero ------
// grid 2665 x 256.  Wfrag/Wofrag in MFMA-fragment order (uint4 per lane):
//  slot [(kchunk)*nstrip + strip][lane(q*16+ln)] holds bf16 W[row=strip*16+ln]
//  [k = kchunk*32 + q*8 .. +8].  Readers load base + lane*16B: coalesced.
__global__ void k_prep(const float* __restrict__ p1_w, const float* __restrict__ p1_b,
                       const float* __restrict__ bn1_g, const float* __restrict__ bn1_b,
                       const float* __restrict__ bn1_m, const float* __restrict__ bn1_v,
                       const float* __restrict__ off_w,
                       const float* __restrict__ dcn_w, const float* __restrict__ dcn_b,
                       const float* __restrict__ bn2_g, const float* __restrict__ bn2_b,
                       const float* __restrict__ bn2_m, const float* __restrict__ bn2_v,
                       short* __restrict__ p1_wb, short* __restrict__ Wofrag,
                       short* __restrict__ Wfrag,
                       float* __restrict__ bias1f, float* __restrict__ inv2f,
                       float* __restrict__ bias2f, unsigned* __restrict__ XpadU)
{
    int blk = blockIdx.x, t = threadIdx.x;
    if (blk == 0) {
        float inv1 = bn1_g[t] / sqrtf(bn1_v[t] + 1e-5f);
        bias1f[t] = p1_b[t] * inv1 + bn1_b[t] - bn1_m[t] * inv1;
        float inv2 = bn2_g[t] / sqrtf(bn2_v[t] + 1e-5f);
        inv2f[t] = inv2;
        bias2f[t] = dcn_b[t] * inv2 + bn2_b[t] - bn2_m[t] * inv2;
    } else if (blk <= 256) {                        // p1_wb row o (bn1 folded)
        int o = blk - 1;
        float inv1 = bn1_g[o] / sqrtf(bn1_v[o] + 1e-5f);
        p1_wb[o*256 + t] = f2bs(p1_w[o*256 + t] * inv1);
    } else if (blk <= 512) {                        // Wfrag for dcn weights
        int o = blk - 257;
        const float* src = dcn_w + (size_t)o*2304;  // [c*9+tap]
        uint4* dst = (uint4*)Wfrag;
        int strip = o >> 4, lnn = o & 15;
        #pragma unroll
        for (int r = 0; r < 2; ++r) {
            int j = r*256 + t;                      // k-octet 0..287
            if (j < 288) {
                int tap = j >> 5, c0 = (j & 31) * 8;
                union { short s[8]; uint4 u; } v;
                #pragma unroll
                for (int e = 0; e < 8; ++e)
                    v.s[e] = f2bs(src[(c0 + e)*9 + tap]);
                dst[(size_t)((j >> 2)*16 + strip)*64 + (j & 3)*16 + lnn] = v.u;
            }
        }
    } else if (blk <= 584) {                        // Wofrag: off weights, frag order
        int gidx = (blk - 513)*256 + t;             // 0..18431
        int kc = gidx >> 7;                         // k-chunk 0..143
        int rem = gidx & 127;
        int strip = rem >> 6, lane2 = rem & 63;
        int ln2 = lane2 & 15, q2 = lane2 >> 4;
        int row = strip*16 + ln2;
        union { short s[8]; uint4 u; } v;
        #pragma unroll
        for (int e = 0; e < 8; ++e) {
            int k = kc*32 + q2*8 + e;
            int tap = k >> 9, ci = k & 511;
            v.s[e] = (row < 27) ? f2bs(off_w[(size_t)row*4608 + ci*9 + tap]) : (short)0;
        }
        ((uint4*)Wofrag)[gidx] = v.u;               // [kc*2+strip][lane2]
    } else {
        int hb = blk - 585;                         // halo zero, 260 cells/b
        int b = hb / 260, i = hb % 260;
        int y, x;
        if (i < 66)       { y = 0;  x = i; }
        else if (i < 132) { y = 65; x = i - 66; }
        else { int j = i - 132; y = 1 + (j >> 1); x = (j & 1) * 65; }
        XpadU[((size_t)(b*66 + y)*66 + x)*256 + t] = 0u;
    }
}

// ---------------- fused transpose+flip + proj: one block per (b,h) row -------
// grid 512 (bid = h*8 + b, XCD-affine) x 512 thr (8 waves).  [R10 version]
__global__ __launch_bounds__(512, 2) void k_fproj(
    const float* __restrict__ feature, short* Xpad,
    const short* __restrict__ p1_wb, const float* __restrict__ bias1f)
{
    __shared__ __align__(16) unsigned char sh_u[16640];  // union: tile | Ash
    __shared__ __align__(16) short Bt[8][2048];          // 32 KB B in frag layout
    float (*tile)[65] = (float(*)[65])sh_u;              // 16.6 KB
    short* Ash = (short*)sh_u;                           // 16 KB
    int bid = blockIdx.x;
    int b = bid & 7, h = bid >> 3;
    int t = threadIdx.x;
    int lane = t & 63, w = t >> 6;
    int lw = t & 63, li = t >> 6;                        // 8 waves: li 0..7
    int ln = lane & 15, q = lane >> 4;
    int r16 = lane >> 2;
    int sq  = (lane & 3) ^ ((lane >> 3) & 3);
    int rq  = (q ^ ((ln >> 1) & 3)) * 8;
    size_t rowbase = (size_t)(b*66 + h + 1)*66;

    // ---- phase 1: transpose+flip, 4 passes of 64 channels ----
    for (int cg = 0; cg < 4; ++cg) {
        int c0 = cg * 64;
        #pragma unroll
        for (int j = 0; j < 8; ++j) {
            int cl = j*8 + li;                           // channel within group
            tile[cl][63 - lw] = feature[((b*256 + c0 + cl)*64 + h)*64 + lw];
        }
        __syncthreads();
        #pragma unroll
        for (int j = 0; j < 8; ++j) {
            int x = j*8 + li;                            // output position
            short s  = f2bs(tile[lw][x]);                // = feature[c0+lw][63-x]
            Xpad[(rowbase + x + 1)*512 + c0 + lw] = s;   // flip half (global)
            short sB = f2bs(tile[lw][63 - x]);           // = feature[c0+lw][x]
            int c = c0 + lw;
            int kt = c >> 5, kk = c & 31, p = kk >> 3, e = kk & 7;
            Bt[kt][x*32 + ((p ^ ((x >> 1) & 3)) << 3) + e] = sB;
        }
        __syncthreads();
    }

    // ---- phase 2: proj GEMM, B from Bt ----
    f32x4 acc[2][4] = {};
    for (int kt = 0; kt < 8; ++kt) {
        int kcol = kt*32 + sq*8;
        #pragma unroll
        for (int i = 0; i < 2; ++i) {
            int row = w*32 + i*16 + r16;
            gl2lds16(p1_wb + (size_t)row*256 + kcol, Ash + (w*32 + i*16)*32);
        }
        __syncthreads();
        short8 af[2], bfr[4];
        #pragma unroll
        for (int i = 0; i < 2; ++i)
            af[i] = *(const short8*)&Ash[(w*32 + i*16 + ln)*32 + rq];
        #pragma unroll
        for (int j = 0; j < 4; ++j)
            bfr[j] = *(const short8*)&Bt[kt][(j*16 + ln)*32 + rq];
        #pragma unroll
        for (int i = 0; i < 2; ++i)
            #pragma unroll
            for (int j = 0; j < 4; ++j)
                acc[i][j] = __builtin_amdgcn_mfma_f32_16x16x32_bf16(af[i], bfr[j], acc[i][j], 0, 0, 0);
        __syncthreads();
    }
    #pragma unroll
    for (int i = 0; i < 2; ++i) {
        int ob = w*32 + i*16 + q*4;
        #pragma unroll
        for (int j = 0; j < 4; ++j) {
            int x = j*16 + ln;
            size_t xb = (rowbase + x + 1)*512 + 256 + ob;
            short4v st;
            st.x = f2bs(acc[i][j][0] + bias1f[ob]);
            st.y = f2bs(acc[i][j][1] + bias1f[ob+1]);
            st.z = f2bs(acc[i][j][2] + bias1f[ob+2]);
            st.w = f2bs(acc[i][j][3] + bias1f[ob+3]);
            *(short4v*)&Xpad[xb] = st;
        }
    }
}

// ---------------- FUSED offset conv + sample + dcn GEMM ----------------------
// grid 512 (bid = h*8 + b, XCD-affine) x 512 thr (8 waves).
// LDS UNION (R12->R13): BshO (32 KB, phase-A only) shares storage with
// {Bsh, c_pk, c_w} (19.25 KB, post-phase-A only). Total LDS 59.9 -> 39.8 KB
// => 4 blocks/CU (was 2). VGPR_Count was already exactly 64 (the 8-wave/SIMD
// cap), so __launch_bounds__(512,8) doubles resident waves for free.
// Aliasing fence: last BshO read (phase-A MFMA) is separated from the first
// c_pk/c_w write by the post-red __syncthreads.
#define ALOAD4(kn_, A_)                                                   \
    A_##0 = Wf4[(size_t)(((kn_)*2+0)*16 + tw0)*64 + lane];                \
    A_##1 = Wf4[(size_t)(((kn_)*2+0)*16 + tw1)*64 + lane];                \
    A_##2 = Wf4[(size_t)(((kn_)*2+1)*16 + tw0)*64 + lane];                \
    A_##3 = Wf4[(size_t)(((kn_)*2+1)*16 + tw1)*64 + lane];

#define MMPHASE(A_)                                                       \
    {                                                                     \
        short8 af00 = *(short8*)&A_##0, af01 = *(short8*)&A_##1;          \
        short8 af10 = *(short8*)&A_##2, af11 = *(short8*)&A_##3;          \
        short8 bfr;                                                       \
        _Pragma("unroll")                                                 \
        for (int jj = 0; jj < 4; ++jj) {                                  \
            bfr = *(const short8*)&Bsh[0][(jj*16 + ln)*32 + rq];          \
            acc[0][jj] = __builtin_amdgcn_mfma_f32_16x16x32_bf16(af00, bfr, acc[0][jj], 0, 0, 0); \
            acc[1][jj] = __builtin_amdgcn_mfma_f32_16x16x32_bf16(af01, bfr, acc[1][jj], 0, 0, 0); \
        }                                                                 \
        _Pragma("unroll")                                                 \
        for (int jj = 0; jj < 4; ++jj) {                                  \
            bfr = *(const short8*)&Bsh[1][(jj*16 + ln)*32 + rq];          \
            acc[0][jj] = __builtin_amdgcn_mfma_f32_16x16x32_bf16(af10, bfr, acc[0][jj], 0, 0, 0); \
            acc[1][jj] = __builtin_amdgcn_mfma_f32_16x16x32_bf16(af11, bfr, acc[1][jj], 0, 0, 0); \
        }                                                                 \
    }

#define WINX(kc2_, AC_, AN_, UC_, VN_)                                    \
    {                                                                     \
        int kn_ = (kc2_) < 35 ? (kc2_) + 1 : 35;                          \
        ALOAD4(kn_, AN_);                                                 \
        GATHER(kn_, VN_);                                                 \
        __builtin_amdgcn_sched_barrier(0);                                \
        BLEND(UC_, (kc2_) >> 2);                                          \
        lds_barrier();                                                    \
        MMPHASE(AC_);                                                     \
        hard_barrier();                                                   \
    }

__global__ __launch_bounds__(512, 8) void k_gemm(
    const short* __restrict__ Xpad,   // flip half: gathers; proj half: residual
    const short* __restrict__ Wfrag,  // fragment-ordered dcn weights
    const uint4* __restrict__ Wof4,   // fragment-ordered offset weights
    const float* __restrict__ off_b,
    const float* __restrict__ inv2f, const float* __restrict__ bias2f,
    float* __restrict__ out)
{
    __shared__ __align__(16) unsigned char shU[32768]; // BshO | {Bsh,c_pk,c_w}
    __shared__ float red[27][65];                      // 6.9 KB offm result
    short (*BshO)[2048] = (short(*)[2048])shU;         // 32 KB, phase A only
    short (*Bsh)[2048]  = (short(*)[2048])shU;         //  8 KB, phase B
    unsigned* c_pk = (unsigned*)(shU + 8192);          // 2.25 KB
    float*    c_w  = (float*)(shU + 10496);            //  9 KB (16-aligned)
    int bid = blockIdx.x;
    int b = bid & 7, h = bid >> 3;                   // XCD-affine b
    int t = threadIdx.x;
    int lane = t & 63, w = t >> 6;
    int ln = lane & 15, q = lane >> 4;
    int rq  = (q ^ ((ln >> 1) & 3)) * 8;
    int tw0 = w*2, tw1 = w*2 + 1;
    const uint4* Wf4 = (const uint4*)Wfrag;

    // ---- phase A: offset conv, result -> red ----
    {
        int wr = w >> 2, wc = w & 3;
        int r16 = lane >> 2;
        int sq  = (lane & 3) ^ ((lane >> 3) & 3);
        const short* xb = Xpad + (size_t)b*XPB;
        f32x4 oacc = {};
        for (int it = 0; it < 18; ++it) {
            int tap = it >> 1;
            int dy = tap/3 - 1, dx = tap%3 - 1;
            uint4 a[8];
            #pragma unroll
            for (int s = 0; s < 8; ++s)
                a[s] = Wof4[(size_t)((it*8 + s)*2 + wr)*64 + lane];
            {   // B staging: wave w -> subchunk w
                int k = it*256 + w*32;
                #pragma unroll
                for (int g = 0; g < 4; ++g) {
                    int row = g*16 + r16;
                    const short* gB = xb + ((size_t)(h + 1 + dy)*66 + (row + dx + 1))*512
                                         + (k & 511) + sq*8;
                    gl2lds16(gB, &BshO[w][(g*16)*32]);
                }
            }
            __syncthreads();
            #pragma unroll
            for (int s = 0; s < 8; ++s) {
                short8 af  = *(short8*)&a[s];
                short8 bfr = *(const short8*)&BshO[s][(wc*16 + ln)*32 + rq];
                oacc = __builtin_amdgcn_mfma_f32_16x16x32_bf16(af, bfr, oacc, 0, 0, 0);
            }
            __syncthreads();
        }
        int x = wc*16 + ln;
        #pragma unroll
        for (int r = 0; r < 4; ++r) {
            int oc = wr*16 + q*4 + r;
            if (oc < 27)
                red[oc][x] = oacc[r] + off_b[oc];
        }
    }
    __syncthreads();   // fences BshO reads before c_pk/c_w (aliased) writes

    // ---- sampling metadata: 64 positions x 9 taps (from red, not global) ----
    for (int e = t; e < 576; e += 512) {
        int p = e / 9, k = e % 9;
        float dy = red[k][p];
        float dx = red[9+k][p];
        float ms = red[18+k][p];
        ms = 1.f / (1.f + expf(-ms));
        float py = (float)h + (float)(k/3 - 1) + dy;
        float px = (float)p + (float)(k%3 - 1) + dx;
        float y0f = floorf(py), x0f = floorf(px);
        float wy = py - y0f, wx = px - x0f;
        int y0 = (int)y0f, x0 = (int)x0f;
        int y1 = y0 + 1, x1 = x0 + 1;
        float vy0 = (y0 >= 0 && y0 < 64) ? 1.f : 0.f;
        float vy1 = (y1 >= 0 && y1 < 64) ? 1.f : 0.f;
        float vx0 = (x0 >= 0 && x0 < 64) ? 1.f : 0.f;
        float vx1 = (x1 >= 0 && x1 < 64) ? 1.f : 0.f;
        int y0c = min(max(y0,0),63), y1c = min(max(y1,0),63);
        int x0c = min(max(x0,0),63), x1c = min(max(x1,0),63);
        unsigned cell = (unsigned)(((y0c+1)*66 + x0c+1)*128);   // uint2 units < 2^20
        unsigned sx = (x1c != x0c) ? 1u : 0u;
        unsigned sy = (y1c != y0c) ? 1u : 0u;
        c_pk[e] = cell | (sx << 20) | (sy << 21);
        c_w[e*4+0] = ms * (1.f-wy)*(1.f-wx) * vy0*vx0;
        c_w[e*4+1] = ms * (1.f-wy)*wx       * vy0*vx1;
        c_w[e*4+2] = ms * wy*(1.f-wx)       * vy1*vx0;
        c_w[e*4+3] = ms * wy*wx             * vy1*vx1;
    }
    __syncthreads();

    // ---- phase B: dcn GEMM with in-kernel bilinear im2col ----
    const uint2* fT = (const uint2*)Xpad + (size_t)b*(XPB/4);
    int pr = t >> 3;                    // B row (position) this thread fills
    int jo = t & 7;                     // channel octet within 64-col window
    int pe9 = pr*9;
    short* bdst = &Bsh[jo >> 2][pr*32 + (((jo & 3) ^ ((pr >> 1) & 3)) << 3)];

    f32x4 acc[2][4] = {};
    uint4 U[4], V[4];
    uint4 a00, a01, a02, a03;           // A fragment regs, window-ping
    uint4 a10, a11, a12, a13;           // A fragment regs, window-pong

    auto GATHER = [&](int win, uint4 (&dst)[4]) {
        unsigned pw = c_pk[pe9 + (win >> 2)];
        int o00 = pw & 0xFFFFF;
        int dxs = (pw >> 13) & 128;                            // sx*128
        int dys = ((pw >> 8) & 0x2000) | ((pw >> 13) & 0x100); // sy*8448
        int cin = ((win & 3) << 4) + jo*2;
        const uint2* p0 = fT + (o00 + cin);
        dst[0] = *(const uint4*)(p0);
        dst[1] = *(const uint4*)(p0 + dxs);
        dst[2] = *(const uint4*)(p0 + dys);
        dst[3] = *(const uint4*)(p0 + dys + dxs);
    };
    auto BLEND = [&](uint4 (&uc)[4], int tap) {
        const float4 cw = *(const float4*)&c_w[(pe9 + tap)*4];
        f32x2 Wx; Wx.x = cw.x; Wx.y = cw.x;
        f32x2 Wy; Wy.x = cw.y; Wy.y = cw.y;
        f32x2 Wz; Wz.x = cw.z; Wz.y = cw.z;
        f32x2 Ww; Ww.x = cw.w; Ww.y = cw.w;
        f32x2 G0 = Wx*up2(uc[0].x) + Wy*up2(uc[1].x) + Wz*up2(uc[2].x) + Ww*up2(uc[3].x);
        f32x2 G1 = Wx*up2(uc[0].y) + Wy*up2(uc[1].y) + Wz*up2(uc[2].y) + Ww*up2(uc[3].y);
        f32x2 G2 = Wx*up2(uc[0].z) + Wy*up2(uc[1].z) + Wz*up2(uc[2].z) + Ww*up2(uc[3].z);
        f32x2 G3 = Wx*up2(uc[0].w) + Wy*up2(uc[1].w) + Wz*up2(uc[2].w) + Ww*up2(uc[3].w);
        uint4 pkv;
        pkv.x = pk2rn(G0.x, G0.y);
        pkv.y = pk2rn(G1.x, G1.y);
        pkv.z = pk2rn(G2.x, G2.y);
        pkv.w = pk2rn(G3.x, G3.y);
        *(uint4*)bdst = pkv;
    };

    ALOAD4(0, a0);
    GATHER(0, U);
    __builtin_amdgcn_sched_barrier(0);
    #pragma unroll 1
    for (int kc2 = 0; kc2 < 36; kc2 += 2) {
        WINX(kc2,     a0, a1, U, V);
        WINX(kc2 + 1, a1, a0, V, U);
    }

    // epilogue: bn2 + residual(from Xpad proj half) + relu
    #pragma unroll
    for (int i = 0; i < 2; ++i) {
        int ob = w*32 + i*16 + q*4;
        #pragma unroll
        for (int jj = 0; jj < 4; ++jj) {
            int p = jj*16 + ln;
            size_t xb = ((size_t)(b*66 + h + 1)*66 + p + 1)*512 + 256 + ob;
            short4v prr = *(const short4v*)&Xpad[xb];
            #pragma unroll
            for (int r = 0; r < 4; ++r) {
                int o = ob + r;
                size_t idx = ((size_t)(b*256 + o))*4096 + h*64 + p;
                float rs = bs2f(((const short*)&prr)[r]);
                float v = rs + acc[i][jj][r]*inv2f[o] + bias2f[o];
                out[idx] = v < 0.f ? 0.f : v;   // NaN-propagating relu
            }
        }
    }
}

extern "C" void kernel_launch(void* const* d_in, const int* in_sizes, int n_in,
                              void* d_out, int out_size, void* d_ws, size_t ws_size,
                              hipStream_t stream)
{
    const float* feature = (const float*)d_in[0];
    const float* p1_w  = (const float*)d_in[1];
    const float* p1_b  = (const float*)d_in[2];
    const float* bn1_g = (const float*)d_in[3];
    const float* bn1_b = (const float*)d_in[4];
    const float* bn1_m = (const float*)d_in[5];
    const float* bn1_v = (const float*)d_in[6];
    const float* off_w = (const float*)d_in[7];
    const float* off_b = (const float*)d_in[8];
    const float* dcn_w = (const float*)d_in[9];
    const float* dcn_b = (const float*)d_in[10];
    const float* bn2_g = (const float*)d_in[11];
    const float* bn2_b = (const float*)d_in[12];
    const float* bn2_m = (const float*)d_in[13];
    const float* bn2_v = (const float*)d_in[14];

    // Workspace (float-slot offsets).
    float* ws = (float*)d_ws;
    short* Xpad   = (short*)ws;                 // 17,842,176 sh = 8,921,088 f
    short* p1_wb  = (short*)(ws + 9805824);     //     65,536 sh = 32,768 f
    short* Wofrag = (short*)(ws + 9838592);     //    147,456 sh = 73,728 f
    short* Wfrag  = (short*)(ws + 9912320);     //    589,824 sh = 294,912 f
    float* bias1f = ws + 10207232;              //        256
    float* inv2f  = ws + 10207488;              //        256
    float* bias2f = ws + 10207744;              //        256

    k_prep<<<2665, 256, 0, stream>>>(p1_w, p1_b, bn1_g, bn1_b, bn1_m, bn1_v,
                                     off_w, dcn_w, dcn_b, bn2_g, bn2_b, bn2_m, bn2_v,
                                     p1_wb, Wofrag, Wfrag, bias1f, inv2f, bias2f,
                                     (unsigned*)Xpad);
    k_fproj<<<512, 512, 0, stream>>>(feature, Xpad, p1_wb, bias1f);
    k_gemm<<<512, 512, 0, stream>>>(Xpad, Wfrag, (const uint4*)Wofrag, off_b,
                                    inv2f, bias2f, (float*)d_out);
}

// Round 14
// 214.756 us; speedup vs baseline: 3.5691x; 3.5691x over previous
//
#include <hip/hip_runtime.h>
#include <hip/hip_bf16.h>
#include <math.h>

typedef __attribute__((ext_vector_type(8))) short short8;
typedef __attribute__((ext_vector_type(4))) short short4v;
typedef __attribute__((ext_vector_type(4))) float f32x4;
typedef __attribute__((ext_vector_type(2))) float f32x2;

__device__ __forceinline__ float bs2f(short s){
    union { unsigned u; float f; } x; x.u = ((unsigned)(unsigned short)s) << 16; return x.f;
}
__device__ __forceinline__ short f2bs(float f){
    union { float f; unsigned u; } x; x.f = f;
    unsigned r = x.u + 0x7fff + ((x.u >> 16) & 1);   // round-nearest-even
    return (short)(r >> 16);
}
__device__ __forceinline__ f32x2 up2(unsigned u){   // unpack 2 bf16 -> float2
    union { unsigned u; float f; } lo, hi;
    lo.u = u << 16; hi.u = u & 0xffff0000u;
    f32x2 r; r.x = lo.f; r.y = hi.f; return r;
}
__device__ __forceinline__ unsigned pk2rn(float lo, float hi){  // RNE pack
    __hip_bfloat162 h = __float22bfloat162_rn(make_float2(lo, hi));
    union { __hip_bfloat162 h; unsigned u; } cv; cv.h = h; return cv.u;
}
__device__ __forceinline__ void gl2lds16(const void* g, void* l){
    __builtin_amdgcn_global_load_lds(
        (const __attribute__((address_space(1))) void*)g,
        (__attribute__((address_space(3))) void*)l, 16, 0, 0);
}
__device__ __forceinline__ void hard_barrier(){
    __builtin_amdgcn_sched_barrier(0);
    __builtin_amdgcn_s_barrier();
    __builtin_amdgcn_sched_barrier(0);
}
// barrier that drains ONLY LDS ops (keeps global register-loads in flight)
__device__ __forceinline__ void lds_barrier(){
    __builtin_amdgcn_sched_barrier(0);
    asm volatile("s_waitcnt lgkmcnt(0)" ::: "memory");
    __builtin_amdgcn_s_barrier();
    __builtin_amdgcn_sched_barrier(0);
}

// Xpad[b][y][x][c]: y,x in [0,66), c in [0,512). Interior (y=h+1,x=w+1).
// c<256: flipped feature (= feature[b][c][h][63-w]); c>=256: proj.
#define XPB ((size_t)66*66*512)

// LDS k-quad XOR swizzle (B tiles): LDS quad p of row r holds global quad
// p^((r>>1)&3); fragment read for (row ln, quad q) uses LDS quad q^((ln>>1)&3).

// ---------------- prep: BN folding + weight transposes + Xpad halo zero ------
// grid 2665 x 256.  Wfrag/Wofrag in MFMA-fragment order (uint4 per lane):
//  slot [(kchunk)*nstrip + strip][lane(q*16+ln)] holds bf16 W[row=strip*16+ln]
//  [k = kchunk*32 + q*8 .. +8].  Readers load base + lane*16B: coalesced.
__global__ void k_prep(const float* __restrict__ p1_w, const float* __restrict__ p1_b,
                       const float* __restrict__ bn1_g, const float* __restrict__ bn1_b,
                       const float* __restrict__ bn1_m, const float* __restrict__ bn1_v,
                       const float* __restrict__ off_w,
                       const float* __restrict__ dcn_w, const float* __restrict__ dcn_b,
                       const float* __restrict__ bn2_g, const float* __restrict__ bn2_b,
                       const float* __restrict__ bn2_m, const float* __restrict__ bn2_v,
                       short* __restrict__ p1_wb, short* __restrict__ Wofrag,
                       short* __restrict__ Wfrag,
                       float* __restrict__ bias1f, float* __restrict__ inv2f,
                       float* __restrict__ bias2f, unsigned* __restrict__ XpadU)
{
    int blk = blockIdx.x, t = threadIdx.x;
    if (blk == 0) {
        float inv1 = bn1_g[t] / sqrtf(bn1_v[t] + 1e-5f);
        bias1f[t] = p1_b[t] * inv1 + bn1_b[t] - bn1_m[t] * inv1;
        float inv2 = bn2_g[t] / sqrtf(bn2_v[t] + 1e-5f);
        inv2f[t] = inv2;
        bias2f[t] = dcn_b[t] * inv2 + bn2_b[t] - bn2_m[t] * inv2;
    } else if (blk <= 256) {                        // p1_wb row o (bn1 folded)
        int o = blk - 1;
        float inv1 = bn1_g[o] / sqrtf(bn1_v[o] + 1e-5f);
        p1_wb[o*256 + t] = f2bs(p1_w[o*256 + t] * inv1);
    } else if (blk <= 512) {                        // Wfrag for dcn weights
        int o = blk - 257;
        const float* src = dcn_w + (size_t)o*2304;  // [c*9+tap]
        uint4* dst = (uint4*)Wfrag;
        int strip = o >> 4, lnn = o & 15;
        #pragma unroll
        for (int r = 0; r < 2; ++r) {
            int j = r*256 + t;                      // k-octet 0..287
            if (j < 288) {
                int tap = j >> 5, c0 = (j & 31) * 8;
                union { short s[8]; uint4 u; } v;
                #pragma unroll
                for (int e = 0; e < 8; ++e)
                    v.s[e] = f2bs(src[(c0 + e)*9 + tap]);
                dst[(size_t)((j >> 2)*16 + strip)*64 + (j & 3)*16 + lnn] = v.u;
            }
        }
    } else if (blk <= 584) {                        // Wofrag: off weights, frag order
        int gidx = (blk - 513)*256 + t;             // 0..18431
        int kc = gidx >> 7;                         // k-chunk 0..143
        int rem = gidx & 127;
        int strip = rem >> 6, lane2 = rem & 63;
        int ln2 = lane2 & 15, q2 = lane2 >> 4;
        int row = strip*16 + ln2;
        union { short s[8]; uint4 u; } v;
        #pragma unroll
        for (int e = 0; e < 8; ++e) {
            int k = kc*32 + q2*8 + e;
            int tap = k >> 9, ci = k & 511;
            v.s[e] = (row < 27) ? f2bs(off_w[(size_t)row*4608 + ci*9 + tap]) : (short)0;
        }
        ((uint4*)Wofrag)[gidx] = v.u;               // [kc*2+strip][lane2]
    } else {
        int hb = blk - 585;                         // halo zero, 260 cells/b
        int b = hb / 260, i = hb % 260;
        int y, x;
        if (i < 66)       { y = 0;  x = i; }
        else if (i < 132) { y = 65; x = i - 66; }
        else { int j = i - 132; y = 1 + (j >> 1); x = (j & 1) * 65; }
        XpadU[((size_t)(b*66 + y)*66 + x)*256 + t] = 0u;
    }
}

// ---------------- fused transpose+flip + proj: one block per (b,h) row -------
// grid 512 (bid = h*8 + b, XCD-affine) x 512 thr (8 waves).  [R10 version]
__global__ __launch_bounds__(512, 2) void k_fproj(
    const float* __restrict__ feature, short* Xpad,
    const short* __restrict__ p1_wb, const float* __restrict__ bias1f)
{
    __shared__ __align__(16) unsigned char sh_u[16640];  // union: tile | Ash
    __shared__ __align__(16) short Bt[8][2048];          // 32 KB B in frag layout
    float (*tile)[65] = (float(*)[65])sh_u;              // 16.6 KB
    short* Ash = (short*)sh_u;                           // 16 KB
    int bid = blockIdx.x;
    int b = bid & 7, h = bid >> 3;
    int t = threadIdx.x;
    int lane = t & 63, w = t >> 6;
    int lw = t & 63, li = t >> 6;                        // 8 waves: li 0..7
    int ln = lane & 15, q = lane >> 4;
    int r16 = lane >> 2;
    int sq  = (lane & 3) ^ ((lane >> 3) & 3);
    int rq  = (q ^ ((ln >> 1) & 3)) * 8;
    size_t rowbase = (size_t)(b*66 + h + 1)*66;

    // ---- phase 1: transpose+flip, 4 passes of 64 channels ----
    for (int cg = 0; cg < 4; ++cg) {
        int c0 = cg * 64;
        #pragma unroll
        for (int j = 0; j < 8; ++j) {
            int cl = j*8 + li;                           // channel within group
            tile[cl][63 - lw] = feature[((b*256 + c0 + cl)*64 + h)*64 + lw];
        }
        __syncthreads();
        #pragma unroll
        for (int j = 0; j < 8; ++j) {
            int x = j*8 + li;                            // output position
            short s  = f2bs(tile[lw][x]);                // = feature[c0+lw][63-x]
            Xpad[(rowbase + x + 1)*512 + c0 + lw] = s;   // flip half (global)
            short sB = f2bs(tile[lw][63 - x]);           // = feature[c0+lw][x]
            int c = c0 + lw;
            int kt = c >> 5, kk = c & 31, p = kk >> 3, e = kk & 7;
            Bt[kt][x*32 + ((p ^ ((x >> 1) & 3)) << 3) + e] = sB;
        }
        __syncthreads();
    }

    // ---- phase 2: proj GEMM, B from Bt ----
    f32x4 acc[2][4] = {};
    for (int kt = 0; kt < 8; ++kt) {
        int kcol = kt*32 + sq*8;
        #pragma unroll
        for (int i = 0; i < 2; ++i) {
            int row = w*32 + i*16 + r16;
            gl2lds16(p1_wb + (size_t)row*256 + kcol, Ash + (w*32 + i*16)*32);
        }
        __syncthreads();
        short8 af[2], bfr[4];
        #pragma unroll
        for (int i = 0; i < 2; ++i)
            af[i] = *(const short8*)&Ash[(w*32 + i*16 + ln)*32 + rq];
        #pragma unroll
        for (int j = 0; j < 4; ++j)
            bfr[j] = *(const short8*)&Bt[kt][(j*16 + ln)*32 + rq];
        #pragma unroll
        for (int i = 0; i < 2; ++i)
            #pragma unroll
            for (int j = 0; j < 4; ++j)
                acc[i][j] = __builtin_amdgcn_mfma_f32_16x16x32_bf16(af[i], bfr[j], acc[i][j], 0, 0, 0);
        __syncthreads();
    }
    #pragma unroll
    for (int i = 0; i < 2; ++i) {
        int ob = w*32 + i*16 + q*4;
        #pragma unroll
        for (int j = 0; j < 4; ++j) {
            int x = j*16 + ln;
            size_t xb = (rowbase + x + 1)*512 + 256 + ob;
            short4v st;
            st.x = f2bs(acc[i][j][0] + bias1f[ob]);
            st.y = f2bs(acc[i][j][1] + bias1f[ob+1]);
            st.z = f2bs(acc[i][j][2] + bias1f[ob+2]);
            st.w = f2bs(acc[i][j][3] + bias1f[ob+3]);
            *(short4v*)&Xpad[xb] = st;
        }
    }
}

// ---------------- FUSED offset conv + sample + dcn GEMM ----------------------
// grid 512 (bid = h*8 + b, XCD-affine) x 512 thr (8 waves).
// LDS UNION: BshO (32 KB, phase-A only) shares storage with {Bsh, c_pk, c_w}
// (19.25 KB, post-phase-A only). Total LDS 39.8 KB => 4 blocks/CU.
// __launch_bounds__(512,4): R13 lesson -- (512,8) capped the allocator below
// the kernel's ~64-VGPR live state and spilled 3 GB to scratch (660 us).
// At bound 4 the same code measured exactly 64 VGPR (R12), which permits
// 8 waves/SIMD; LDS is now the occupancy limiter at 4 blocks/CU.
#define ALOAD4(kn_, A_)                                                   \
    A_##0 = Wf4[(size_t)(((kn_)*2+0)*16 + tw0)*64 + lane];                \
    A_##1 = Wf4[(size_t)(((kn_)*2+0)*16 + tw1)*64 + lane];                \
    A_##2 = Wf4[(size_t)(((kn_)*2+1)*16 + tw0)*64 + lane];                \
    A_##3 = Wf4[(size_t)(((kn_)*2+1)*16 + tw1)*64 + lane];

#define MMPHASE(A_)                                                       \
    {                                                                     \
        short8 af00 = *(short8*)&A_##0, af01 = *(short8*)&A_##1;          \
        short8 af10 = *(short8*)&A_##2, af11 = *(short8*)&A_##3;          \
        short8 bfr;                                                       \
        _Pragma("unroll")                                                 \
        for (int jj = 0; jj < 4; ++jj) {                                  \
            bfr = *(const short8*)&Bsh[0][(jj*16 + ln)*32 + rq];          \
            acc[0][jj] = __builtin_amdgcn_mfma_f32_16x16x32_bf16(af00, bfr, acc[0][jj], 0, 0, 0); \
            acc[1][jj] = __builtin_amdgcn_mfma_f32_16x16x32_bf16(af01, bfr, acc[1][jj], 0, 0, 0); \
        }                                                                 \
        _Pragma("unroll")                                                 \
        for (int jj = 0; jj < 4; ++jj) {                                  \
            bfr = *(const short8*)&Bsh[1][(jj*16 + ln)*32 + rq];          \
            acc[0][jj] = __builtin_amdgcn_mfma_f32_16x16x32_bf16(af10, bfr, acc[0][jj], 0, 0, 0); \
            acc[1][jj] = __builtin_amdgcn_mfma_f32_16x16x32_bf16(af11, bfr, acc[1][jj], 0, 0, 0); \
        }                                                                 \
    }

#define WINX(kc2_, AC_, AN_, UC_, VN_)                                    \
    {                                                                     \
        int kn_ = (kc2_) < 35 ? (kc2_) + 1 : 35;                          \
        ALOAD4(kn_, AN_);                                                 \
        GATHER(kn_, VN_);                                                 \
        __builtin_amdgcn_sched_barrier(0);                                \
        BLEND(UC_, (kc2_) >> 2);                                          \
        lds_barrier();                                                    \
        MMPHASE(AC_);                                                     \
        hard_barrier();                                                   \
    }

__global__ __launch_bounds__(512, 4) void k_gemm(
    const short* __restrict__ Xpad,   // flip half: gathers; proj half: residual
    const short* __restrict__ Wfrag,  // fragment-ordered dcn weights
    const uint4* __restrict__ Wof4,   // fragment-ordered offset weights
    const float* __restrict__ off_b,
    const float* __restrict__ inv2f, const float* __restrict__ bias2f,
    float* __restrict__ out)
{
    __shared__ __align__(16) unsigned char shU[32768]; // BshO | {Bsh,c_pk,c_w}
    __shared__ float red[27][65];                      // 6.9 KB offm result
    short (*BshO)[2048] = (short(*)[2048])shU;         // 32 KB, phase A only
    short (*Bsh)[2048]  = (short(*)[2048])shU;         //  8 KB, phase B
    unsigned* c_pk = (unsigned*)(shU + 8192);          // 2.25 KB
    float*    c_w  = (float*)(shU + 10496);            //  9 KB (16-aligned)
    int bid = blockIdx.x;
    int b = bid & 7, h = bid >> 3;                   // XCD-affine b
    int t = threadIdx.x;
    int lane = t & 63, w = t >> 6;
    int ln = lane & 15, q = lane >> 4;
    int rq  = (q ^ ((ln >> 1) & 3)) * 8;
    int tw0 = w*2, tw1 = w*2 + 1;
    const uint4* Wf4 = (const uint4*)Wfrag;

    // ---- phase A: offset conv, result -> red ----
    {
        int wr = w >> 2, wc = w & 3;
        int r16 = lane >> 2;
        int sq  = (lane & 3) ^ ((lane >> 3) & 3);
        const short* xb = Xpad + (size_t)b*XPB;
        f32x4 oacc = {};
        for (int it = 0; it < 18; ++it) {
            int tap = it >> 1;
            int dy = tap/3 - 1, dx = tap%3 - 1;
            uint4 a[8];
            #pragma unroll
            for (int s = 0; s < 8; ++s)
                a[s] = Wof4[(size_t)((it*8 + s)*2 + wr)*64 + lane];
            {   // B staging: wave w -> subchunk w
                int k = it*256 + w*32;
                #pragma unroll
                for (int g = 0; g < 4; ++g) {
                    int row = g*16 + r16;
                    const short* gB = xb + ((size_t)(h + 1 + dy)*66 + (row + dx + 1))*512
                                         + (k & 511) + sq*8;
                    gl2lds16(gB, &BshO[w][(g*16)*32]);
                }
            }
            __syncthreads();
            #pragma unroll
            for (int s = 0; s < 8; ++s) {
                short8 af  = *(short8*)&a[s];
                short8 bfr = *(const short8*)&BshO[s][(wc*16 + ln)*32 + rq];
                oacc = __builtin_amdgcn_mfma_f32_16x16x32_bf16(af, bfr, oacc, 0, 0, 0);
            }
            __syncthreads();
        }
        int x = wc*16 + ln;
        #pragma unroll
        for (int r = 0; r < 4; ++r) {
            int oc = wr*16 + q*4 + r;
            if (oc < 27)
                red[oc][x] = oacc[r] + off_b[oc];
        }
    }
    __syncthreads();   // fences BshO reads before c_pk/c_w (aliased) writes

    // ---- sampling metadata: 64 positions x 9 taps (from red, not global) ----
    for (int e = t; e < 576; e += 512) {
        int p = e / 9, k = e % 9;
        float dy = red[k][p];
        float dx = red[9+k][p];
        float ms = red[18+k][p];
        ms = 1.f / (1.f + expf(-ms));
        float py = (float)h + (float)(k/3 - 1) + dy;
        float px = (float)p + (float)(k%3 - 1) + dx;
        float y0f = floorf(py), x0f = floorf(px);
        float wy = py - y0f, wx = px - x0f;
        int y0 = (int)y0f, x0 = (int)x0f;
        int y1 = y0 + 1, x1 = x0 + 1;
        float vy0 = (y0 >= 0 && y0 < 64) ? 1.f : 0.f;
        float vy1 = (y1 >= 0 && y1 < 64) ? 1.f : 0.f;
        float vx0 = (x0 >= 0 && x0 < 64) ? 1.f : 0.f;
        float vx1 = (x1 >= 0 && x1 < 64) ? 1.f : 0.f;
        int y0c = min(max(y0,0),63), y1c = min(max(y1,0),63);
        int x0c = min(max(x0,0),63), x1c = min(max(x1,0),63);
        unsigned cell = (unsigned)(((y0c+1)*66 + x0c+1)*128);   // uint2 units < 2^20
        unsigned sx = (x1c != x0c) ? 1u : 0u;
        unsigned sy = (y1c != y0c) ? 1u : 0u;
        c_pk[e] = cell | (sx << 20) | (sy << 21);
        c_w[e*4+0] = ms * (1.f-wy)*(1.f-wx) * vy0*vx0;
        c_w[e*4+1] = ms * (1.f-wy)*wx       * vy0*vx1;
        c_w[e*4+2] = ms * wy*(1.f-wx)       * vy1*vx0;
        c_w[e*4+3] = ms * wy*wx             * vy1*vx1;
    }
    __syncthreads();

    // ---- phase B: dcn GEMM with in-kernel bilinear im2col ----
    const uint2* fT = (const uint2*)Xpad + (size_t)b*(XPB/4);
    int pr = t >> 3;                    // B row (position) this thread fills
    int jo = t & 7;                     // channel octet within 64-col window
    int pe9 = pr*9;
    short* bdst = &Bsh[jo >> 2][pr*32 + (((jo & 3) ^ ((pr >> 1) & 3)) << 3)];

    f32x4 acc[2][4] = {};
    uint4 U[4], V[4];
    uint4 a00, a01, a02, a03;           // A fragment regs, window-ping
    uint4 a10, a11, a12, a13;           // A fragment regs, window-pong

    auto GATHER = [&](int win, uint4 (&dst)[4]) {
        unsigned pw = c_pk[pe9 + (win >> 2)];
        int o00 = pw & 0xFFFFF;
        int dxs = (pw >> 13) & 128;                            // sx*128
        int dys = ((pw >> 8) & 0x2000) | ((pw >> 13) & 0x100); // sy*8448
        int cin = ((win & 3) << 4) + jo*2;
        const uint2* p0 = fT + (o00 + cin);
        dst[0] = *(const uint4*)(p0);
        dst[1] = *(const uint4*)(p0 + dxs);
        dst[2] = *(const uint4*)(p0 + dys);
        dst[3] = *(const uint4*)(p0 + dys + dxs);
    };
    auto BLEND = [&](uint4 (&uc)[4], int tap) {
        const float4 cw = *(const float4*)&c_w[(pe9 + tap)*4];
        f32x2 Wx; Wx.x = cw.x; Wx.y = cw.x;
        f32x2 Wy; Wy.x = cw.y; Wy.y = cw.y;
        f32x2 Wz; Wz.x = cw.z; Wz.y = cw.z;
        f32x2 Ww; Ww.x = cw.w; Ww.y = cw.w;
        f32x2 G0 = Wx*up2(uc[0].x) + Wy*up2(uc[1].x) + Wz*up2(uc[2].x) + Ww*up2(uc[3].x);
        f32x2 G1 = Wx*up2(uc[0].y) + Wy*up2(uc[1].y) + Wz*up2(uc[2].y) + Ww*up2(uc[3].y);
        f32x2 G2 = Wx*up2(uc[0].z) + Wy*up2(uc[1].z) + Wz*up2(uc[2].z) + Ww*up2(uc[3].z);
        f32x2 G3 = Wx*up2(uc[0].w) + Wy*up2(uc[1].w) + Wz*up2(uc[2].w) + Ww*up2(uc[3].w);
        uint4 pkv;
        pkv.x = pk2rn(G0.x, G0.y);
        pkv.y = pk2rn(G1.x, G1.y);
        pkv.z = pk2rn(G2.x, G2.y);
        pkv.w = pk2rn(G3.x, G3.y);
        *(uint4*)bdst = pkv;
    };

    ALOAD4(0, a0);
    GATHER(0, U);
    __builtin_amdgcn_sched_barrier(0);
    #pragma unroll 1
    for (int kc2 = 0; kc2 < 36; kc2 += 2) {
        WINX(kc2,     a0, a1, U, V);
        WINX(kc2 + 1, a1, a0, V, U);
    }

    // epilogue: bn2 + residual(from Xpad proj half) + relu
    #pragma unroll
    for (int i = 0; i < 2; ++i) {
        int ob = w*32 + i*16 + q*4;
        #pragma unroll
        for (int jj = 0; jj < 4; ++jj) {
            int p = jj*16 + ln;
            size_t xb = ((size_t)(b*66 + h + 1)*66 + p + 1)*512 + 256 + ob;
            short4v prr = *(const short4v*)&Xpad[xb];
            #pragma unroll
            for (int r = 0; r < 4; ++r) {
                int o = ob + r;
                size_t idx = ((size_t)(b*256 + o))*4096 + h*64 + p;
                float rs = bs2f(((const short*)&prr)[r]);
                float v = rs + acc[i][jj][r]*inv2f[o] + bias2f[o];
                out[idx] = v < 0.f ? 0.f : v;   // NaN-propagating relu
            }
        }
    }
}

extern "C" void kernel_launch(void* const* d_in, const int* in_sizes, int n_in,
                              void* d_out, int out_size, void* d_ws, size_t ws_size,
                              hipStream_t stream)
{
    const float* feature = (const float*)d_in[0];
    const float* p1_w  = (const float*)d_in[1];
    const float* p1_b  = (const float*)d_in[2];
    const float* bn1_g = (const float*)d_in[3];
    const float* bn1_b = (const float*)d_in[4];
    const float* bn1_m = (const float*)d_in[5];
    const float* bn1_v = (const float*)d_in[6];
    const float* off_w = (const float*)d_in[7];
    const float* off_b = (const float*)d_in[8];
    const float* dcn_w = (const float*)d_in[9];
    const float* dcn_b = (const float*)d_in[10];
    const float* bn2_g = (const float*)d_in[11];
    const float* bn2_b = (const float*)d_in[12];
    const float* bn2_m = (const float*)d_in[13];
    const float* bn2_v = (const float*)d_in[14];

    // Workspace (float-slot offsets).
    float* ws = (float*)d_ws;
    short* Xpad   = (short*)ws;                 // 17,842,176 sh = 8,921,088 f
    short* p1_wb  = (short*)(ws + 9805824);     //     65,536 sh = 32,768 f
    short* Wofrag = (short*)(ws + 9838592);     //    147,456 sh = 73,728 f
    short* Wfrag  = (short*)(ws + 9912320);     //    589,824 sh = 294,912 f
    float* bias1f = ws + 10207232;              //        256
    float* inv2f  = ws + 10207488;              //        256
    float* bias2f = ws + 10207744;              //        256

    k_prep<<<2665, 256, 0, stream>>>(p1_w, p1_b, bn1_g, bn1_b, bn1_m, bn1_v,
                                     off_w, dcn_w, dcn_b, bn2_g, bn2_b, bn2_m, bn2_v,
                                     p1_wb, Wofrag, Wfrag, bias1f, inv2f, bias2f,
                                     (unsigned*)Xpad);
    k_fproj<<<512, 512, 0, stream>>>(feature, Xpad, p1_wb, bias1f);
    k_gemm<<<512, 512, 0, stream>>>(Xpad, Wfrag, (const uint4*)Wofrag, off_b,
                                    inv2f, bias2f, (float*)d_out);
}